// Round 7
// baseline (359.257 us; speedup 1.0000x reference)
//
#include <hip/hip_runtime.h>
#include <math.h>

#define N_NODES 100000
#define N_EDGES 800000
#define E_TOT (N_EDGES + N_NODES)
#define NEG_SLOPE 0.2f
#define SCAN_NB ((N_NODES + 1023) / 1024)

typedef unsigned short ushort_t;
typedef __attribute__((ext_vector_type(8))) short short8v;   // 8 bf16
typedef __attribute__((ext_vector_type(4))) float f32x4;

static __device__ __forceinline__ float leaky(float e) {
  return e > 0.f ? e : NEG_SLOPE * e;
}

static __device__ __forceinline__ float b2f(ushort_t u) {
  union { unsigned int i; float f; } x;
  x.i = ((unsigned int)u) << 16;
  return x.f;
}

static __device__ __forceinline__ ushort_t f2b(float f) {
  union { float f; unsigned int i; } x;
  x.f = f;
  unsigned int r = x.i + 0x7FFFu + ((x.i >> 16) & 1u);  // RNE (finite inputs)
  return (ushort_t)(r >> 16);
}

// ---------------- CSR build ----------------

__global__ void degree_kernel(const int* __restrict__ ei, int* __restrict__ deg) {
  int e = blockIdx.x * 256 + threadIdx.x;
  if (e >= E_TOT) return;
  int d = (e < N_EDGES) ? ei[N_EDGES + e] : (e - N_EDGES);
  atomicAdd(&deg[d], 1);
}

__global__ __launch_bounds__(1024) void scan_p1(const int* __restrict__ deg,
                                                int* __restrict__ blockSums) {
  int i = blockIdx.x * 1024 + threadIdx.x;
  int v = (i < N_NODES) ? deg[i] : 0;
#pragma unroll
  for (int off = 32; off; off >>= 1) v += __shfl_xor(v, off);
  __shared__ int wsum[16];
  if ((threadIdx.x & 63) == 0) wsum[threadIdx.x >> 6] = v;
  __syncthreads();
  if (threadIdx.x == 0) {
    int s = 0;
#pragma unroll
    for (int w = 0; w < 16; ++w) s += wsum[w];
    blockSums[blockIdx.x] = s;
  }
}

__global__ void scan_p2(const int* __restrict__ blockSums, int* __restrict__ blockOffs) {
  if (threadIdx.x == 0) {
    int s = 0;
    for (int b = 0; b < SCAN_NB; ++b) { blockOffs[b] = s; s += blockSums[b]; }
  }
}

__global__ __launch_bounds__(1024) void scan_p3(const int* __restrict__ deg,
                                                const int* __restrict__ blockOffs,
                                                int* __restrict__ rowptr,
                                                int* __restrict__ fillpos) {
  __shared__ int sh[1024];
  int i = blockIdx.x * 1024 + threadIdx.x;
  int v = (i < N_NODES) ? deg[i] : 0;
  sh[threadIdx.x] = v;
  __syncthreads();
  for (int off = 1; off < 1024; off <<= 1) {
    int t = (threadIdx.x >= off) ? sh[threadIdx.x - off] : 0;
    __syncthreads();
    sh[threadIdx.x] += t;
    __syncthreads();
  }
  if (i < N_NODES) {
    int excl = sh[threadIdx.x] - v + blockOffs[blockIdx.x];
    rowptr[i] = excl;
    fillpos[i] = excl;
    if (i == N_NODES - 1) rowptr[N_NODES] = excl + v;
  }
}

__global__ void fill_kernel(const int* __restrict__ ei, int* __restrict__ fillpos,
                            int* __restrict__ col) {
  int e = blockIdx.x * 256 + threadIdx.x;
  if (e >= E_TOT) return;
  int s, d;
  if (e < N_EDGES) { s = ei[e]; d = ei[N_EDGES + e]; }
  else { s = d = e - N_EDGES; }
  int p = atomicAdd(&fillpos[d], 1);
  col[p] = s;
}

// ---------------- weight transpose + bf16 cast (tiny) ----------------

__global__ void transpose_cast(const float* __restrict__ W, ushort_t* __restrict__ Wt,
                               int K, int Nc) {
  int i = blockIdx.x * 256 + threadIdx.x;
  if (i >= K * Nc) return;
  int n = i / K, k = i - n * K;
  Wt[i] = f2b(W[(size_t)k * Nc + n]);   // Wt[n][k] = W[k][n]
}

// ---------------- MFMA GEMM: Out[M][NTOT](bf16) = A[M][KTOT] @ Bt^T ----------------

template <int WAVES_M, int WAVES_N, int KTOT, bool A_FP32>
__global__ __launch_bounds__(256) void mfma_gemm(
    const void* __restrict__ Aptr, const ushort_t* __restrict__ Bt,
    ushort_t* __restrict__ Out, int M, int NTOT) {
  constexpr int BM = 128;
  constexpr int WN = 64;
  constexpr int WM = BM / WAVES_M;
  constexpr int M_REP = WM / 16;
  constexpr int N_REP = WN / 16;
  constexpr int KC = 128;
  __shared__ ushort_t As[BM * KC];

  const int tid = threadIdx.x;
  const int lane = tid & 63;
  const int wid = tid >> 6;
  const int wm = wid % WAVES_M;
  const int wn = wid / WAVES_M;
  const int rowBase = blockIdx.x * BM;
  const int colBase = blockIdx.y * (WAVES_N * WN) + wn * WN;
  const int l15 = lane & 15;
  const int l4 = lane >> 4;

  f32x4 acc[M_REP][N_REP] = {};

  for (int kc = 0; kc < KTOT; kc += KC) {
    if (kc) __syncthreads();
    for (int c = tid; c < BM * KC / 8; c += 256) {
      int r = c >> 4;
      int k8 = (c & 15) << 3;
      int gr = rowBase + r;
      short8v u = {};
      if (gr < M) {
        if (A_FP32) {
          const float* A = (const float*)Aptr;
          float4 f0 = *(const float4*)&A[(size_t)gr * KTOT + kc + k8];
          float4 f1 = *(const float4*)&A[(size_t)gr * KTOT + kc + k8 + 4];
          u[0] = (short)f2b(f0.x); u[1] = (short)f2b(f0.y);
          u[2] = (short)f2b(f0.z); u[3] = (short)f2b(f0.w);
          u[4] = (short)f2b(f1.x); u[5] = (short)f2b(f1.y);
          u[6] = (short)f2b(f1.z); u[7] = (short)f2b(f1.w);
        } else {
          const ushort_t* A = (const ushort_t*)Aptr;
          u = *(const short8v*)&A[(size_t)gr * KTOT + kc + k8];
        }
      }
      int byte = (r * KC + k8) * 2;
      byte ^= (r & 7) << 4;  // G4 swizzle
      *(short8v*)((char*)As + byte) = u;
    }
    short8v bfr[KC / 32][N_REP];
#pragma unroll
    for (int kk = 0; kk < KC / 32; ++kk)
#pragma unroll
      for (int n = 0; n < N_REP; ++n) {
        int bcol = colBase + n * 16 + l15;
        int k0 = kc + kk * 32 + l4 * 8;
        bfr[kk][n] = *(const short8v*)&Bt[(size_t)bcol * KTOT + k0];
      }
    __syncthreads();
#pragma unroll
    for (int kk = 0; kk < KC / 32; ++kk) {
      short8v afr[M_REP];
#pragma unroll
      for (int m = 0; m < M_REP; ++m) {
        int r = wm * WM + m * 16 + l15;
        int k0 = kk * 32 + l4 * 8;
        int byte = ((r * KC + k0) * 2) ^ ((r & 7) << 4);
        afr[m] = *(const short8v*)((const char*)As + byte);
      }
#pragma unroll
      for (int m = 0; m < M_REP; ++m)
#pragma unroll
        for (int n = 0; n < N_REP; ++n)
          acc[m][n] = __builtin_amdgcn_mfma_f32_16x16x32_bf16(
              afr[m], bfr[kk][n], acc[m][n], 0, 0, 0);
    }
  }
#pragma unroll
  for (int m = 0; m < M_REP; ++m) {
    int r0 = rowBase + wm * WM + m * 16 + l4 * 4;
#pragma unroll
    for (int n = 0; n < N_REP; ++n) {
      int gc = colBase + n * 16 + l15;
#pragma unroll
      for (int j = 0; j < 4; ++j) {
        int gr = r0 + j;
        if (gr < M) Out[(size_t)gr * NTOT + gc] = f2b(acc[m][n][j]);
      }
    }
  }
}

// ---------------- per-node attention scalars (bf16 h) ----------------

template <int C>
__global__ __launch_bounds__(256) void alpha_kernel(
    const ushort_t* __restrict__ h, const float* __restrict__ vs,
    const float* __restrict__ vd, float* __restrict__ os, float* __restrict__ od) {
  int n = blockIdx.x * 4 + (threadIdx.x >> 6);
  if (n >= N_NODES) return;
  int lane = threadIdx.x & 63;
  float ps = 0.f, pd = 0.f;
  if (C == 256) {
    ushort4 u = *reinterpret_cast<const ushort4*>(&h[(size_t)n * 256 + lane * 4]);
    float f0 = b2f(u.x), f1 = b2f(u.y), f2 = b2f(u.z), f3 = b2f(u.w);
    ps = f0 * vs[lane * 4] + f1 * vs[lane * 4 + 1] + f2 * vs[lane * 4 + 2] + f3 * vs[lane * 4 + 3];
    pd = f0 * vd[lane * 4] + f1 * vd[lane * 4 + 1] + f2 * vd[lane * 4 + 2] + f3 * vd[lane * 4 + 3];
  } else {
    float f = b2f(h[(size_t)n * 64 + lane]);
    ps = f * vs[lane];
    pd = f * vd[lane];
  }
#pragma unroll
  for (int off = 32; off; off >>= 1) {
    ps += __shfl_xor(ps, off);
    pd += __shfl_xor(pd, off);
  }
  if (lane == 0) { os[n] = ps; od[n] = pd; }
}

// ---------------- fused softmax + aggregation ----------------
// No-max softmax (e bounded; exp fits fp32). Pass A: lane l computes exp of
// edge l, wave-reduce denom, store PRE-NORMALIZED weight to LDS (one write).
// Pass B: 8 gathers in flight; weights read as 2x ds_read_b128 at wave-uniform
// address (broadcast, no bpermute, no per-edge mul).

// layer 1: lane = 4 channels (C=256); fused relu(acc + b1) -> bf16 out
__global__ __launch_bounds__(256) void fused_agg1(
    const ushort_t* __restrict__ h, const int* __restrict__ rowptr,
    const int* __restrict__ col, const float* __restrict__ asrc,
    const float* __restrict__ adst, const float* __restrict__ bias,
    ushort_t* __restrict__ out) {
  __shared__ float wlds[4][64];
  int wid = threadIdx.x >> 6;
  int n = blockIdx.x * 4 + wid;
  if (n >= N_NODES) return;
  int lane = threadIdx.x & 63;
  int beg = rowptr[n], end = rowptr[n + 1];
  int deg = end - beg;
  float ad = adst[n];
  // pass A
  float we = 0.f;
  if (lane < deg) we = __expf(leaky(asrc[col[beg + lane]] + ad));
  float ssum = we;
  for (int jj = beg + 64 + lane; jj < end; jj += 64)   // essentially never
    ssum += __expf(leaky(asrc[col[jj]] + ad));
#pragma unroll
  for (int off = 32; off; off >>= 1) ssum += __shfl_xor(ssum, off);
  float inv = 1.0f / ssum;
  wlds[wid][lane] = we * inv;   // same-wave write->read; lgkmcnt handled by compiler
  // pass B
  float a0 = 0.f, a1 = 0.f, a2 = 0.f, a3 = 0.f;
  if (deg <= 64) {
    int t = 0;
    for (; t + 8 <= deg; t += 8) {
      int s0 = col[beg + t],     s1 = col[beg + t + 1];
      int s2 = col[beg + t + 2], s3 = col[beg + t + 3];
      int s4 = col[beg + t + 4], s5 = col[beg + t + 5];
      int s6 = col[beg + t + 6], s7 = col[beg + t + 7];
      float4 wA = *reinterpret_cast<const float4*>(&wlds[wid][t]);
      float4 wB = *reinterpret_cast<const float4*>(&wlds[wid][t + 4]);
      ushort4 u0 = *reinterpret_cast<const ushort4*>(&h[(size_t)s0 * 256 + lane * 4]);
      ushort4 u1 = *reinterpret_cast<const ushort4*>(&h[(size_t)s1 * 256 + lane * 4]);
      ushort4 u2 = *reinterpret_cast<const ushort4*>(&h[(size_t)s2 * 256 + lane * 4]);
      ushort4 u3 = *reinterpret_cast<const ushort4*>(&h[(size_t)s3 * 256 + lane * 4]);
      ushort4 u4 = *reinterpret_cast<const ushort4*>(&h[(size_t)s4 * 256 + lane * 4]);
      ushort4 u5 = *reinterpret_cast<const ushort4*>(&h[(size_t)s5 * 256 + lane * 4]);
      ushort4 u6 = *reinterpret_cast<const ushort4*>(&h[(size_t)s6 * 256 + lane * 4]);
      ushort4 u7 = *reinterpret_cast<const ushort4*>(&h[(size_t)s7 * 256 + lane * 4]);
      a0 += wA.x * b2f(u0.x) + wA.y * b2f(u1.x) + wA.z * b2f(u2.x) + wA.w * b2f(u3.x)
          + wB.x * b2f(u4.x) + wB.y * b2f(u5.x) + wB.z * b2f(u6.x) + wB.w * b2f(u7.x);
      a1 += wA.x * b2f(u0.y) + wA.y * b2f(u1.y) + wA.z * b2f(u2.y) + wA.w * b2f(u3.y)
          + wB.x * b2f(u4.y) + wB.y * b2f(u5.y) + wB.z * b2f(u6.y) + wB.w * b2f(u7.y);
      a2 += wA.x * b2f(u0.z) + wA.y * b2f(u1.z) + wA.z * b2f(u2.z) + wA.w * b2f(u3.z)
          + wB.x * b2f(u4.z) + wB.y * b2f(u5.z) + wB.z * b2f(u6.z) + wB.w * b2f(u7.z);
      a3 += wA.x * b2f(u0.w) + wA.y * b2f(u1.w) + wA.z * b2f(u2.w) + wA.w * b2f(u3.w)
          + wB.x * b2f(u4.w) + wB.y * b2f(u5.w) + wB.z * b2f(u6.w) + wB.w * b2f(u7.w);
    }
    for (; t < deg; ++t) {
      int s = col[beg + t];
      float w = wlds[wid][t];
      ushort4 u = *reinterpret_cast<const ushort4*>(&h[(size_t)s * 256 + lane * 4]);
      a0 += w * b2f(u.x); a1 += w * b2f(u.y);
      a2 += w * b2f(u.z); a3 += w * b2f(u.w);
    }
  } else {  // deg > 64: recompute weights (astronomically rare)
    for (int j = beg; j < end; ++j) {
      int s = col[j];
      float w = __expf(leaky(asrc[s] + ad)) * inv;
      ushort4 u = *reinterpret_cast<const ushort4*>(&h[(size_t)s * 256 + lane * 4]);
      a0 += w * b2f(u.x); a1 += w * b2f(u.y);
      a2 += w * b2f(u.z); a3 += w * b2f(u.w);
    }
  }
  float4 bv = *reinterpret_cast<const float4*>(&bias[lane * 4]);
  ushort4 o;
  o.x = f2b(fmaxf(a0 + bv.x, 0.f));
  o.y = f2b(fmaxf(a1 + bv.y, 0.f));
  o.z = f2b(fmaxf(a2 + bv.z, 0.f));
  o.w = f2b(fmaxf(a3 + bv.w, 0.f));
  *reinterpret_cast<ushort4*>(&out[(size_t)n * 256 + lane * 4]) = o;
}

// layer 2: lane = 1 channel (C=64); fused +bias, final fp32 output
__global__ __launch_bounds__(256) void fused_agg2(
    const ushort_t* __restrict__ h, const int* __restrict__ rowptr,
    const int* __restrict__ col, const float* __restrict__ asrc,
    const float* __restrict__ adst, const float* __restrict__ bias,
    float* __restrict__ out) {
  __shared__ float wlds[4][64];
  int wid = threadIdx.x >> 6;
  int n = blockIdx.x * 4 + wid;
  if (n >= N_NODES) return;
  int lane = threadIdx.x & 63;
  int beg = rowptr[n], end = rowptr[n + 1];
  int deg = end - beg;
  float ad = adst[n];
  float we = 0.f;
  if (lane < deg) we = __expf(leaky(asrc[col[beg + lane]] + ad));
  float ssum = we;
  for (int jj = beg + 64 + lane; jj < end; jj += 64)
    ssum += __expf(leaky(asrc[col[jj]] + ad));
#pragma unroll
  for (int off = 32; off; off >>= 1) ssum += __shfl_xor(ssum, off);
  float inv = 1.0f / ssum;
  wlds[wid][lane] = we * inv;
  float acc = 0.f;
  if (deg <= 64) {
    int t = 0;
    for (; t + 8 <= deg; t += 8) {
      int s0 = col[beg + t],     s1 = col[beg + t + 1];
      int s2 = col[beg + t + 2], s3 = col[beg + t + 3];
      int s4 = col[beg + t + 4], s5 = col[beg + t + 5];
      int s6 = col[beg + t + 6], s7 = col[beg + t + 7];
      float4 wA = *reinterpret_cast<const float4*>(&wlds[wid][t]);
      float4 wB = *reinterpret_cast<const float4*>(&wlds[wid][t + 4]);
      ushort_t u0 = h[(size_t)s0 * 64 + lane];
      ushort_t u1 = h[(size_t)s1 * 64 + lane];
      ushort_t u2 = h[(size_t)s2 * 64 + lane];
      ushort_t u3 = h[(size_t)s3 * 64 + lane];
      ushort_t u4 = h[(size_t)s4 * 64 + lane];
      ushort_t u5 = h[(size_t)s5 * 64 + lane];
      ushort_t u6 = h[(size_t)s6 * 64 + lane];
      ushort_t u7 = h[(size_t)s7 * 64 + lane];
      acc += wA.x * b2f(u0) + wA.y * b2f(u1) + wA.z * b2f(u2) + wA.w * b2f(u3)
           + wB.x * b2f(u4) + wB.y * b2f(u5) + wB.z * b2f(u6) + wB.w * b2f(u7);
    }
    for (; t < deg; ++t)
      acc += wlds[wid][t] * b2f(h[(size_t)col[beg + t] * 64 + lane]);
  } else {
    for (int j = beg; j < end; ++j) {
      int s = col[j];
      float w = __expf(leaky(asrc[s] + ad)) * inv;
      acc += w * b2f(h[(size_t)s * 64 + lane]);
    }
  }
  out[(size_t)n * 64 + lane] = acc + bias[lane];
}

// ---------------- launch ----------------

extern "C" void kernel_launch(void* const* d_in, const int* in_sizes, int n_in,
                              void* d_out, int out_size, void* d_ws, size_t ws_size,
                              hipStream_t stream) {
  const float* x    = (const float*)d_in[0];
  const int*   ei   = (const int*)d_in[1];
  const float* W1   = (const float*)d_in[2];
  const float* a1s  = (const float*)d_in[3];
  const float* a1d  = (const float*)d_in[4];
  const float* b1   = (const float*)d_in[5];
  const float* W2   = (const float*)d_in[6];
  const float* a2s  = (const float*)d_in[7];
  const float* a2d  = (const float*)d_in[8];
  const float* b2   = (const float*)d_in[9];
  float* out = (float*)d_out;

  char* ws = (char*)d_ws;
  size_t off = 0;
  auto alloc = [&](size_t bytes) {
    void* p = ws + off;
    off += bytes;
    off = (off + 255) & ~(size_t)255;
    return p;
  };

  ushort_t* h1   = (ushort_t*)alloc((size_t)N_NODES * 256 * 2);  // bf16
  ushort_t* a1b  = (ushort_t*)alloc((size_t)N_NODES * 256 * 2);  // bf16 relu(agg1+b1)
  ushort_t* h2   = (ushort_t*)alloc((size_t)N_NODES * 64 * 2);   // bf16
  ushort_t* W1t  = (ushort_t*)alloc((size_t)256 * 128 * 2);
  ushort_t* W2t  = (ushort_t*)alloc((size_t)64 * 256 * 2);
  float* asrc1   = (float*)alloc((size_t)N_NODES * 4);
  float* adst1   = (float*)alloc((size_t)N_NODES * 4);
  float* asrc2   = (float*)alloc((size_t)N_NODES * 4);
  float* adst2   = (float*)alloc((size_t)N_NODES * 4);
  int*   deg     = (int*)alloc((size_t)N_NODES * 4);
  int*   rowptr  = (int*)alloc((size_t)(N_NODES + 1) * 4);
  int*   fillp   = (int*)alloc((size_t)N_NODES * 4);
  int*   col     = (int*)alloc((size_t)E_TOT * 4);
  int*   bsums   = (int*)alloc((size_t)SCAN_NB * 4);
  int*   boffs   = (int*)alloc((size_t)SCAN_NB * 4);

  const int edgeBlocks = (E_TOT + 255) / 256;
  const int nodeBlocks4 = (N_NODES + 3) / 4;
  const int gemmBlocksM = (N_NODES + 127) / 128;

  // CSR build
  hipMemsetAsync(deg, 0, (size_t)N_NODES * 4, stream);
  degree_kernel<<<edgeBlocks, 256, 0, stream>>>(ei, deg);
  scan_p1<<<SCAN_NB, 1024, 0, stream>>>(deg, bsums);
  scan_p2<<<1, 64, 0, stream>>>(bsums, boffs);
  scan_p3<<<SCAN_NB, 1024, 0, stream>>>(deg, boffs, rowptr, fillp);
  fill_kernel<<<edgeBlocks, 256, 0, stream>>>(ei, fillp, col);

  // weight prep
  transpose_cast<<<(256 * 128 + 255) / 256, 256, 0, stream>>>(W1, W1t, 128, 256);
  transpose_cast<<<(64 * 256 + 255) / 256, 256, 0, stream>>>(W2, W2t, 256, 64);

  // layer 1: h1 = bf16(x) @ bf16(W1)
  mfma_gemm<2, 2, 128, true><<<dim3(gemmBlocksM, 2), 256, 0, stream>>>(
      x, W1t, h1, N_NODES, 256);
  alpha_kernel<256><<<nodeBlocks4, 256, 0, stream>>>(h1, a1s, a1d, asrc1, adst1);
  fused_agg1<<<nodeBlocks4, 256, 0, stream>>>(h1, rowptr, col, asrc1, adst1, b1, a1b);

  // layer 2: h2 = a1b @ bf16(W2)
  mfma_gemm<4, 1, 256, false><<<dim3(gemmBlocksM, 1), 256, 0, stream>>>(
      a1b, W2t, h2, N_NODES, 64);
  alpha_kernel<64><<<nodeBlocks4, 256, 0, stream>>>(h2, a2s, a2d, asrc2, adst2);
  fused_agg2<<<nodeBlocks4, 256, 0, stream>>>(h2, rowptr, col, asrc2, adst2, b2, out);
}

// Round 8
// 314.278 us; speedup vs baseline: 1.1431x; 1.1431x over previous
//
#include <hip/hip_runtime.h>
#include <math.h>

#define N_NODES 100000
#define N_EDGES 800000
#define E_TOT (N_EDGES + N_NODES)
#define NEG_SLOPE 0.2f
#define SCAN_NB ((N_NODES + 1023) / 1024)
#define EB ((E_TOT + 255) / 256)

typedef unsigned short ushort_t;
typedef __attribute__((ext_vector_type(8))) short short8v;   // 8 bf16
typedef __attribute__((ext_vector_type(4))) float f32x4;

static __device__ __forceinline__ float leaky(float e) {
  return e > 0.f ? e : NEG_SLOPE * e;
}

static __device__ __forceinline__ float b2f(ushort_t u) {
  union { unsigned int i; float f; } x;
  x.i = ((unsigned int)u) << 16;
  return x.f;
}

static __device__ __forceinline__ ushort_t f2b(float f) {
  union { float f; unsigned int i; } x;
  x.f = f;
  unsigned int r = x.i + 0x7FFFu + ((x.i >> 16) & 1u);  // RNE (finite inputs)
  return (ushort_t)(r >> 16);
}

// ---------------- prep: degree histogram + both weight transposes ----------------

__global__ void prep_kernel(const int* __restrict__ ei, int* __restrict__ deg,
                            const float* __restrict__ W1, ushort_t* __restrict__ W1t,
                            const float* __restrict__ W2, ushort_t* __restrict__ W2t) {
  int b = blockIdx.x;
  if (b < EB) {
    int e = b * 256 + threadIdx.x;
    if (e >= E_TOT) return;
    int d = (e < N_EDGES) ? ei[N_EDGES + e] : (e - N_EDGES);
    atomicAdd(&deg[d], 1);
  } else if (b < EB + 128) {           // W1t[n][k], n<256 k<128
    int i = (b - EB) * 256 + threadIdx.x;
    int n = i >> 7, k = i & 127;
    W1t[i] = f2b(W1[(size_t)k * 256 + n]);
  } else {                             // W2t[n][k], n<64 k<256
    int i = (b - EB - 128) * 256 + threadIdx.x;
    int n = i >> 8, k = i & 255;
    W2t[i] = f2b(W2[(size_t)k * 64 + n]);
  }
}

// ---------------- scan ----------------

__global__ __launch_bounds__(1024) void scan_p1(const int* __restrict__ deg,
                                                int* __restrict__ blockSums) {
  int i = blockIdx.x * 1024 + threadIdx.x;
  int v = (i < N_NODES) ? deg[i] : 0;
#pragma unroll
  for (int off = 32; off; off >>= 1) v += __shfl_xor(v, off);
  __shared__ int wsum[16];
  if ((threadIdx.x & 63) == 0) wsum[threadIdx.x >> 6] = v;
  __syncthreads();
  if (threadIdx.x == 0) {
    int s = 0;
#pragma unroll
    for (int w = 0; w < 16; ++w) s += wsum[w];
    blockSums[blockIdx.x] = s;
  }
}

// p2+p3 merged: each block computes its own offset (wave-parallel over blockSums)
__global__ __launch_bounds__(1024) void scan_p23(const int* __restrict__ deg,
                                                 const int* __restrict__ blockSums,
                                                 int* __restrict__ rowptr,
                                                 int* __restrict__ fillpos) {
  __shared__ int sh[1024];
  __shared__ int boff;
  int bid = blockIdx.x;
  if (threadIdx.x < 64) {
    int l = threadIdx.x;
    int p = 0;
    if (l < bid) p += blockSums[l];
    if (l + 64 < bid) p += blockSums[l + 64];
#pragma unroll
    for (int o = 32; o; o >>= 1) p += __shfl_xor(p, o);
    if (l == 0) boff = p;
  }
  int i = bid * 1024 + threadIdx.x;
  int v = (i < N_NODES) ? deg[i] : 0;
  sh[threadIdx.x] = v;
  __syncthreads();
  for (int off = 1; off < 1024; off <<= 1) {
    int t = (threadIdx.x >= off) ? sh[threadIdx.x - off] : 0;
    __syncthreads();
    sh[threadIdx.x] += t;
    __syncthreads();
  }
  if (i < N_NODES) {
    int excl = sh[threadIdx.x] - v + boff;
    rowptr[i] = excl;
    fillpos[i] = excl;
    if (i == N_NODES - 1) rowptr[N_NODES] = excl + v;
  }
}

__global__ void fill_kernel(const int* __restrict__ ei, int* __restrict__ fillpos,
                            int* __restrict__ col) {
  int e = blockIdx.x * 256 + threadIdx.x;
  if (e >= E_TOT) return;
  int s, d;
  if (e < N_EDGES) { s = ei[e]; d = ei[N_EDGES + e]; }
  else { s = d = e - N_EDGES; }
  int p = atomicAdd(&fillpos[d], 1);
  col[p] = s;
}

// ---------------- MFMA GEMM with fused alpha epilogue ----------------
// ALPHA_MODE 1: per-row partial dots with av_s/av_d over this block's col
//   slice; LDS-reduce across waves, 2 global atomicAdds per row (exactly 2
//   contributions per address across grid.y -> bitwise deterministic).
// ALPHA_MODE 2: block covers ALL cols (NTOT<=64): complete dot in-wave,
//   direct store, no atomics.

template <int WAVES_M, int WAVES_N, int KTOT, bool A_FP32, int ALPHA_MODE>
__global__ __launch_bounds__(256) void mfma_gemm(
    const void* __restrict__ Aptr, const ushort_t* __restrict__ Bt,
    ushort_t* __restrict__ Out, int M, int NTOT,
    const float* __restrict__ av_s, const float* __restrict__ av_d,
    float* __restrict__ os, float* __restrict__ od) {
  constexpr int BM = 128;
  constexpr int WN = 64;
  constexpr int WM = BM / WAVES_M;
  constexpr int M_REP = WM / 16;
  constexpr int N_REP = WN / 16;
  constexpr int KC = 128;
  __shared__ ushort_t As[BM * KC];
  __shared__ float als_s[BM], als_d[BM];

  const int tid = threadIdx.x;
  const int lane = tid & 63;
  const int wid = tid >> 6;
  const int wm = wid % WAVES_M;
  const int wn = wid / WAVES_M;
  const int rowBase = blockIdx.x * BM;
  const int colBase = blockIdx.y * (WAVES_N * WN) + wn * WN;
  const int l15 = lane & 15;
  const int l4 = lane >> 4;

  if (ALPHA_MODE == 1) {
    for (int rr = tid; rr < BM; rr += 256) { als_s[rr] = 0.f; als_d[rr] = 0.f; }
  }

  f32x4 acc[M_REP][N_REP] = {};

  for (int kc = 0; kc < KTOT; kc += KC) {
    if (kc) __syncthreads();
    for (int c = tid; c < BM * KC / 8; c += 256) {
      int r = c >> 4;
      int k8 = (c & 15) << 3;
      int gr = rowBase + r;
      short8v u = {};
      if (gr < M) {
        if (A_FP32) {
          const float* A = (const float*)Aptr;
          float4 f0 = *(const float4*)&A[(size_t)gr * KTOT + kc + k8];
          float4 f1 = *(const float4*)&A[(size_t)gr * KTOT + kc + k8 + 4];
          u[0] = (short)f2b(f0.x); u[1] = (short)f2b(f0.y);
          u[2] = (short)f2b(f0.z); u[3] = (short)f2b(f0.w);
          u[4] = (short)f2b(f1.x); u[5] = (short)f2b(f1.y);
          u[6] = (short)f2b(f1.z); u[7] = (short)f2b(f1.w);
        } else {
          const ushort_t* A = (const ushort_t*)Aptr;
          u = *(const short8v*)&A[(size_t)gr * KTOT + kc + k8];
        }
      }
      int byte = (r * KC + k8) * 2;
      byte ^= (r & 7) << 4;  // G4 swizzle
      *(short8v*)((char*)As + byte) = u;
    }
    short8v bfr[KC / 32][N_REP];
#pragma unroll
    for (int kk = 0; kk < KC / 32; ++kk)
#pragma unroll
      for (int n = 0; n < N_REP; ++n) {
        int bcol = colBase + n * 16 + l15;
        int k0 = kc + kk * 32 + l4 * 8;
        bfr[kk][n] = *(const short8v*)&Bt[(size_t)bcol * KTOT + k0];
      }
    __syncthreads();
#pragma unroll
    for (int kk = 0; kk < KC / 32; ++kk) {
      short8v afr[M_REP];
#pragma unroll
      for (int m = 0; m < M_REP; ++m) {
        int r = wm * WM + m * 16 + l15;
        int k0 = kk * 32 + l4 * 8;
        int byte = ((r * KC + k0) * 2) ^ ((r & 7) << 4);
        afr[m] = *(const short8v*)((const char*)As + byte);
      }
#pragma unroll
      for (int m = 0; m < M_REP; ++m)
#pragma unroll
        for (int n = 0; n < N_REP; ++n)
          acc[m][n] = __builtin_amdgcn_mfma_f32_16x16x32_bf16(
              afr[m], bfr[kk][n], acc[m][n], 0, 0, 0);
    }
  }
  // C write: col=lane&15, row=(lane>>4)*4+reg
#pragma unroll
  for (int m = 0; m < M_REP; ++m) {
    int r0 = rowBase + wm * WM + m * 16 + l4 * 4;
#pragma unroll
    for (int n = 0; n < N_REP; ++n) {
      int gc = colBase + n * 16 + l15;
#pragma unroll
      for (int j = 0; j < 4; ++j) {
        int gr = r0 + j;
        if (gr < M) Out[(size_t)gr * NTOT + gc] = f2b(acc[m][n][j]);
      }
    }
  }
  // fused alpha epilogue
  if (ALPHA_MODE) {
    float as_v[N_REP], ad_v[N_REP];
#pragma unroll
    for (int n = 0; n < N_REP; ++n) {
      as_v[n] = av_s[colBase + n * 16 + l15];
      ad_v[n] = av_d[colBase + n * 16 + l15];
    }
#pragma unroll
    for (int m = 0; m < M_REP; ++m)
#pragma unroll
      for (int j = 0; j < 4; ++j) {
        float ss = 0.f, dd = 0.f;
#pragma unroll
        for (int n = 0; n < N_REP; ++n) {
          ss += acc[m][n][j] * as_v[n];
          dd += acc[m][n][j] * ad_v[n];
        }
#pragma unroll
        for (int o = 1; o < 16; o <<= 1) {
          ss += __shfl_xor(ss, o);
          dd += __shfl_xor(dd, o);
        }
        if (l15 == 0) {
          int rloc = wm * WM + m * 16 + l4 * 4 + j;
          if (ALPHA_MODE == 1) {
            atomicAdd(&als_s[rloc], ss);
            atomicAdd(&als_d[rloc], dd);
          } else {
            int gr = rowBase + rloc;
            if (gr < M) { os[gr] = ss; od[gr] = dd; }
          }
        }
      }
    if (ALPHA_MODE == 1) {
      __syncthreads();
      for (int rr = tid; rr < BM; rr += 256) {
        int gr = rowBase + rr;
        if (gr < M) {
          atomicAdd(&os[gr], als_s[rr]);
          atomicAdd(&od[gr], als_d[rr]);
        }
      }
    }
  }
}

// ---------------- fused softmax + aggregation ----------------
// Pass A: lane l handles edge l: col + exp; wave-reduce denom; store
// pre-normalized weight AND pre-shifted byte offset to LDS.
// Pass B: 8 gathers in flight; weights+offsets via ds_read_b128 broadcast.

// layer 1: lane = 4 channels (C=256, 512B rows); fused relu(acc+b1) -> bf16
__global__ __launch_bounds__(256) void fused_agg1(
    const ushort_t* __restrict__ h, const int* __restrict__ rowptr,
    const int* __restrict__ col, const float* __restrict__ asrc,
    const float* __restrict__ adst, const float* __restrict__ bias,
    ushort_t* __restrict__ out) {
  __shared__ float wlds[4][64];
  __shared__ int clds[4][64];
  int wid = threadIdx.x >> 6;
  int n = blockIdx.x * 4 + wid;
  if (n >= N_NODES) return;
  int lane = threadIdx.x & 63;
  int beg = rowptr[n], end = rowptr[n + 1];
  int deg = end - beg;
  float ad = adst[n];
  float we = 0.f;
  int s = 0;
  if (lane < deg) { s = col[beg + lane]; we = __expf(leaky(asrc[s] + ad)); }
  float ssum = we;
  for (int jj = beg + 64 + lane; jj < end; jj += 64)   // essentially never
    ssum += __expf(leaky(asrc[col[jj]] + ad));
#pragma unroll
  for (int off = 32; off; off >>= 1) ssum += __shfl_xor(ssum, off);
  float inv = 1.0f / ssum;
  wlds[wid][lane] = we * inv;
  clds[wid][lane] = s << 9;   // byte offset of 512B row
  float a0 = 0.f, a1 = 0.f, a2 = 0.f, a3 = 0.f;
  const char* hb = (const char*)h + lane * 8;
  if (deg <= 64) {
    int t = 0;
    for (; t + 8 <= deg; t += 8) {
      int4 cA = *reinterpret_cast<const int4*>(&clds[wid][t]);
      int4 cB = *reinterpret_cast<const int4*>(&clds[wid][t + 4]);
      float4 wA = *reinterpret_cast<const float4*>(&wlds[wid][t]);
      float4 wB = *reinterpret_cast<const float4*>(&wlds[wid][t + 4]);
      ushort4 u0 = *reinterpret_cast<const ushort4*>(hb + cA.x);
      ushort4 u1 = *reinterpret_cast<const ushort4*>(hb + cA.y);
      ushort4 u2 = *reinterpret_cast<const ushort4*>(hb + cA.z);
      ushort4 u3 = *reinterpret_cast<const ushort4*>(hb + cA.w);
      ushort4 u4 = *reinterpret_cast<const ushort4*>(hb + cB.x);
      ushort4 u5 = *reinterpret_cast<const ushort4*>(hb + cB.y);
      ushort4 u6 = *reinterpret_cast<const ushort4*>(hb + cB.z);
      ushort4 u7 = *reinterpret_cast<const ushort4*>(hb + cB.w);
      a0 += wA.x * b2f(u0.x) + wA.y * b2f(u1.x) + wA.z * b2f(u2.x) + wA.w * b2f(u3.x)
          + wB.x * b2f(u4.x) + wB.y * b2f(u5.x) + wB.z * b2f(u6.x) + wB.w * b2f(u7.x);
      a1 += wA.x * b2f(u0.y) + wA.y * b2f(u1.y) + wA.z * b2f(u2.y) + wA.w * b2f(u3.y)
          + wB.x * b2f(u4.y) + wB.y * b2f(u5.y) + wB.z * b2f(u6.y) + wB.w * b2f(u7.y);
      a2 += wA.x * b2f(u0.z) + wA.y * b2f(u1.z) + wA.z * b2f(u2.z) + wA.w * b2f(u3.z)
          + wB.x * b2f(u4.z) + wB.y * b2f(u5.z) + wB.z * b2f(u6.z) + wB.w * b2f(u7.z);
      a3 += wA.x * b2f(u0.w) + wA.y * b2f(u1.w) + wA.z * b2f(u2.w) + wA.w * b2f(u3.w)
          + wB.x * b2f(u4.w) + wB.y * b2f(u5.w) + wB.z * b2f(u6.w) + wB.w * b2f(u7.w);
    }
    for (; t < deg; ++t) {
      int c = clds[wid][t];
      float w = wlds[wid][t];
      ushort4 u = *reinterpret_cast<const ushort4*>(hb + c);
      a0 += w * b2f(u.x); a1 += w * b2f(u.y);
      a2 += w * b2f(u.z); a3 += w * b2f(u.w);
    }
  } else {  // deg > 64: recompute weights (astronomically rare)
    for (int j = beg; j < end; ++j) {
      int sj = col[j];
      float w = __expf(leaky(asrc[sj] + ad)) * inv;
      ushort4 u = *reinterpret_cast<const ushort4*>(&h[(size_t)sj * 256 + lane * 4]);
      a0 += w * b2f(u.x); a1 += w * b2f(u.y);
      a2 += w * b2f(u.z); a3 += w * b2f(u.w);
    }
  }
  float4 bv = *reinterpret_cast<const float4*>(&bias[lane * 4]);
  ushort4 o;
  o.x = f2b(fmaxf(a0 + bv.x, 0.f));
  o.y = f2b(fmaxf(a1 + bv.y, 0.f));
  o.z = f2b(fmaxf(a2 + bv.z, 0.f));
  o.w = f2b(fmaxf(a3 + bv.w, 0.f));
  *reinterpret_cast<ushort4*>(&out[(size_t)n * 256 + lane * 4]) = o;
}

// layer 2: lane = 1 channel (C=64, 128B rows); fused +bias, final fp32 out
__global__ __launch_bounds__(256) void fused_agg2(
    const ushort_t* __restrict__ h, const int* __restrict__ rowptr,
    const int* __restrict__ col, const float* __restrict__ asrc,
    const float* __restrict__ adst, const float* __restrict__ bias,
    float* __restrict__ out) {
  __shared__ float wlds[4][64];
  __shared__ int clds[4][64];
  int wid = threadIdx.x >> 6;
  int n = blockIdx.x * 4 + wid;
  if (n >= N_NODES) return;
  int lane = threadIdx.x & 63;
  int beg = rowptr[n], end = rowptr[n + 1];
  int deg = end - beg;
  float ad = adst[n];
  float we = 0.f;
  int s = 0;
  if (lane < deg) { s = col[beg + lane]; we = __expf(leaky(asrc[s] + ad)); }
  float ssum = we;
  for (int jj = beg + 64 + lane; jj < end; jj += 64)
    ssum += __expf(leaky(asrc[col[jj]] + ad));
#pragma unroll
  for (int off = 32; off; off >>= 1) ssum += __shfl_xor(ssum, off);
  float inv = 1.0f / ssum;
  wlds[wid][lane] = we * inv;
  clds[wid][lane] = s << 7;   // byte offset of 128B row
  float acc = 0.f;
  const char* hb = (const char*)h + lane * 2;
  if (deg <= 64) {
    int t = 0;
    for (; t + 8 <= deg; t += 8) {
      int4 cA = *reinterpret_cast<const int4*>(&clds[wid][t]);
      int4 cB = *reinterpret_cast<const int4*>(&clds[wid][t + 4]);
      float4 wA = *reinterpret_cast<const float4*>(&wlds[wid][t]);
      float4 wB = *reinterpret_cast<const float4*>(&wlds[wid][t + 4]);
      ushort_t u0 = *reinterpret_cast<const ushort_t*>(hb + cA.x);
      ushort_t u1 = *reinterpret_cast<const ushort_t*>(hb + cA.y);
      ushort_t u2 = *reinterpret_cast<const ushort_t*>(hb + cA.z);
      ushort_t u3 = *reinterpret_cast<const ushort_t*>(hb + cA.w);
      ushort_t u4 = *reinterpret_cast<const ushort_t*>(hb + cB.x);
      ushort_t u5 = *reinterpret_cast<const ushort_t*>(hb + cB.y);
      ushort_t u6 = *reinterpret_cast<const ushort_t*>(hb + cB.z);
      ushort_t u7 = *reinterpret_cast<const ushort_t*>(hb + cB.w);
      acc += wA.x * b2f(u0) + wA.y * b2f(u1) + wA.z * b2f(u2) + wA.w * b2f(u3)
           + wB.x * b2f(u4) + wB.y * b2f(u5) + wB.z * b2f(u6) + wB.w * b2f(u7);
    }
    for (; t < deg; ++t)
      acc += wlds[wid][t] * b2f(*reinterpret_cast<const ushort_t*>(hb + clds[wid][t]));
  } else {
    for (int j = beg; j < end; ++j) {
      int sj = col[j];
      float w = __expf(leaky(asrc[sj] + ad)) * inv;
      acc += w * b2f(h[(size_t)sj * 64 + lane]);
    }
  }
  out[(size_t)n * 64 + lane] = acc + bias[lane];
}

// ---------------- launch ----------------

extern "C" void kernel_launch(void* const* d_in, const int* in_sizes, int n_in,
                              void* d_out, int out_size, void* d_ws, size_t ws_size,
                              hipStream_t stream) {
  const float* x    = (const float*)d_in[0];
  const int*   ei   = (const int*)d_in[1];
  const float* W1   = (const float*)d_in[2];
  const float* a1s  = (const float*)d_in[3];
  const float* a1d  = (const float*)d_in[4];
  const float* b1   = (const float*)d_in[5];
  const float* W2   = (const float*)d_in[6];
  const float* a2s  = (const float*)d_in[7];
  const float* a2d  = (const float*)d_in[8];
  const float* b2   = (const float*)d_in[9];
  float* out = (float*)d_out;

  char* ws = (char*)d_ws;
  size_t off = 0;
  auto alloc = [&](size_t bytes) {
    void* p = ws + off;
    off += bytes;
    off = (off + 255) & ~(size_t)255;
    return p;
  };

  ushort_t* h1   = (ushort_t*)alloc((size_t)N_NODES * 256 * 2);  // bf16
  ushort_t* a1b  = (ushort_t*)alloc((size_t)N_NODES * 256 * 2);  // bf16 relu(agg1+b1)
  ushort_t* h2   = (ushort_t*)alloc((size_t)N_NODES * 64 * 2);   // bf16
  ushort_t* W1t  = (ushort_t*)alloc((size_t)256 * 128 * 2);
  ushort_t* W2t  = (ushort_t*)alloc((size_t)64 * 256 * 2);
  // zero region: asrc1, adst1, deg contiguous (one memset)
  float* asrc1   = (float*)alloc((size_t)N_NODES * 4);
  float* adst1   = (float*)alloc((size_t)N_NODES * 4);
  int*   deg     = (int*)alloc((size_t)N_NODES * 4);
  float* asrc2   = (float*)alloc((size_t)N_NODES * 4);
  float* adst2   = (float*)alloc((size_t)N_NODES * 4);
  int*   rowptr  = (int*)alloc((size_t)(N_NODES + 1) * 4);
  int*   fillp   = (int*)alloc((size_t)N_NODES * 4);
  int*   col     = (int*)alloc((size_t)E_TOT * 4);
  int*   bsums   = (int*)alloc((size_t)SCAN_NB * 4);

  const int nodeBlocks4 = (N_NODES + 3) / 4;
  const int gemmBlocksM = (N_NODES + 127) / 128;
  const size_t zeroBytes = (char*)deg + (size_t)N_NODES * 4 - (char*)asrc1;

  hipMemsetAsync(asrc1, 0, zeroBytes, stream);
  prep_kernel<<<EB + 128 + 64, 256, 0, stream>>>(ei, deg, W1, W1t, W2, W2t);
  scan_p1<<<SCAN_NB, 1024, 0, stream>>>(deg, bsums);
  scan_p23<<<SCAN_NB, 1024, 0, stream>>>(deg, bsums, rowptr, fillp);
  fill_kernel<<<EB, 256, 0, stream>>>(ei, fillp, col);

  // layer 1: h1 = bf16(x) @ W1t^T, alpha partials via atomics
  mfma_gemm<2, 2, 128, true, 1><<<dim3(gemmBlocksM, 2), 256, 0, stream>>>(
      x, W1t, h1, N_NODES, 256, a1s, a1d, asrc1, adst1);
  fused_agg1<<<nodeBlocks4, 256, 0, stream>>>(h1, rowptr, col, asrc1, adst1, b1, a1b);

  // layer 2: h2 = a1b @ W2t^T, alpha direct
  mfma_gemm<4, 1, 256, false, 2><<<dim3(gemmBlocksM, 1), 256, 0, stream>>>(
      a1b, W2t, h2, N_NODES, 64, a2s, a2d, asrc2, adst2);
  fused_agg2<<<nodeBlocks4, 256, 0, stream>>>(h2, rowptr, col, asrc2, adst2, b2, out);
}